// Round 14
// baseline (210.281 us; speedup 1.0000x reference)
//
#include <hip/hip_runtime.h>

// VQ codebook assignment via merged single-accumulator split-f16 MFMA GEMM (K=768 effective),
// R14: 32x32x16 MFMA shape (fewer/fatter ops, 2382 vs 2075 TF ceiling) + n-major phase with
// early operand reloads (kills tail-stall convoy), 64tok/wave, 3 waves/SIMD, half-K LDS-E.
//   x:       [B=32, C=256, H=32, W=32] f32   -> tokens [32768][256]
//   embed_w: [K=2048, C=256] f32
// out f32: quantize [32,256,32,32] (8388608) | embed_index [32,32,32] (32768 as float) | loss [1]=0
//
// Math (verified R11-R13): xh=f16(64x), xl=f16(64x-xh); eh=f16(2^15 e), el=f16(2^15 e - eh).
//   acc = sum xh*eh + xh*el + xl*eh == 2^21*dot - sum(xl*el)  (dropped ~1e-6 rel)
//   d = 2^21*esq - 2*acc ; argmin preserved.
//
// 32x32x16 fragment layout (analog of verified 16x16x32): A/B lane l -> row/col = l&31,
//   k = 8*(l>>5)+e (f16x8 per op). C/D: col = l&31, row = (r&3)+8*(r>>2)+4*(l>>5), r in [0,16).
// Register law: pool 512/SIMD; 3 waves/SIMD => <=170/wave. acc 64 + frags 64 + misc ~20 = ~148.
// R3: no global_load_lds. R9: rotation + setprio. R13: no reg caps below need (tripwire WRITE).
//
// ws fragment-panel layout (32-row tiles, kstep-major):
//   A: [panel 512][kc 8][limb 2][rowtile 2][kstep 2][khalf 2][row 32][16B] = 32 MB (64 tok/panel)
//   E: [panel 32 ][kc 8][limb 2][ntile  2][kstep 2][khalf 2][code 32][16B] =  2 MB (64 codes/panel)

#define CDIM 256
#define KDIM 2048
#define HW   1024
#define NTOK 32768
#define QOFF 8388608
#define LOFF (QOFF + NTOK)

typedef _Float16 f16x8  __attribute__((ext_vector_type(8)));
typedef float    f32x16 __attribute__((ext_vector_type(16)));

__device__ __forceinline__ f16x8 ld16(const char* p) { return *(const f16x8*)(p); }

// ---------------- fused prep: blocks 0..1023 = X transpose, 1024..1279 = E limbs ----------------
__global__ __launch_bounds__(256) void prep_kernel(const float* __restrict__ x,
                                                   const float* __restrict__ ew,
                                                   char* __restrict__ Aws,
                                                   char* __restrict__ Ews,
                                                   float* __restrict__ esq,
                                                   float* __restrict__ out) {
    __shared__ float tile[32][257];
    const int t = threadIdx.x;
    if (blockIdx.x < 1024) {
        const int bid = blockIdx.x;              // 32 b * 8 kc * 4 hwblk
        const int b = bid >> 5;
        const int kc = (bid >> 2) & 7;
        const int c0 = kc * 32;
        const int hw0 = (bid & 3) * 256;
        #pragma unroll 8
        for (int r = 0; r < 32; ++r)
            tile[r][t] = x[((size_t)(b * CDIM + c0 + r) << 10) + hw0 + t];
        __syncthreads();
        union { _Float16 h[32]; uint4 q[4]; } Hb, Lb;
        #pragma unroll 8
        for (int r = 0; r < 32; ++r) {
            const float xs = tile[r][t] * 64.0f;
            const _Float16 hh = (_Float16)xs;
            Hb.h[r] = hh;
            Lb.h[r] = (_Float16)(xs - (float)hh);
        }
        const int tok = b * HW + hw0 + t;
        const int p = tok >> 6, rowtile = (tok >> 5) & 1, row = tok & 31;
        // [kc][limb][rowtile][g=kstep*2+khalf][row][16B]; g covers channels g*8..g*8+7
        char* d = Aws + (size_t)p * 65536 + kc * 8192 + rowtile * 2048 + row * 16;
        #pragma unroll
        for (int g = 0; g < 4; ++g) {
            *(uint4*)(d + g * 512)        = Hb.q[g];   // high limb
            *(uint4*)(d + 4096 + g * 512) = Lb.q[g];   // low limb
        }
    } else {
        const int bid = blockIdx.x - 1024;             // 256 blocks x 8 codes
        const int code = bid * 8 + (t >> 5);
        const int u = t & 31;                          // channels u*8..u*8+7
        const float4 v0 = *(const float4*)&ew[(size_t)code * CDIM + u * 8];
        const float4 v1 = *(const float4*)&ew[(size_t)code * CDIM + u * 8 + 4];
        float s = v0.x*v0.x + v0.y*v0.y + v0.z*v0.z + v0.w*v0.w
                + v1.x*v1.x + v1.y*v1.y + v1.z*v1.z + v1.w*v1.w;
        #pragma unroll
        for (int m = 16; m >= 1; m >>= 1) s += __shfl_xor(s, m, 32);
        if (u == 0) esq[code] = s * 2097152.0f;        // 2^21 * esq
        const float e[8] = {v0.x, v0.y, v0.z, v0.w, v1.x, v1.y, v1.z, v1.w};
        union { _Float16 h[8]; uint4 q; } H, L;
        #pragma unroll
        for (int j = 0; j < 8; ++j) {
            const float ev = e[j] * 32768.0f;          // 2^15 * e
            const _Float16 hh = (_Float16)ev;
            H.h[j] = hh;
            L.h[j] = (_Float16)(ev - (float)hh);
        }
        const int kc = u >> 2, sub = u & 3;            // sub = kstep*2+khalf
        const int p = code >> 6, ntile = (code >> 5) & 1, crow = code & 31;
        char* d = Ews + (size_t)p * 65536 + kc * 8192 + ntile * 2048 + sub * 512 + crow * 16;
        *(uint4*)d = H.q;
        *(uint4*)(d + 4096) = L.q;
        if (bid == 0 && t == 0) out[LOFF] = 0.0f;
    }
}

// ---------------- fused MFMA GEMM + argmin: 32x32x16, n-major early-reload phases ----------------
// Block = 4 waves x 64 tokens (256 tokens) over ONE shared 64-code panel, half-K LDS.
__global__ __launch_bounds__(256, 3) void vqmm_kernel(const char* __restrict__ Aws,
                                                      const char* __restrict__ Ews,
                                                      const float* __restrict__ esq,
                                                      float* __restrict__ cv,
                                                      int* __restrict__ ci) {
    __shared__ __align__(16) char elds[32768];   // one K-half: [kc 4][limb 2][ntile 2][sub 4][code 32][16B]

    const int t = threadIdx.x;
    const int bid = blockIdx.x;                     // 4096 blocks
    // bijective XCD-grouped swizzle: the 32 code-panels of one token-group share bid%8
    const int by = (bid & 7) | ((bid >> 8) << 3);   // token group 0..127 (256 tokens)
    const int bx = (bid >> 3) & 31;                 // code panel 0..31   (64 codes)
    const int lane = t & 63, w = t >> 6;
    const int l5 = lane >> 5, l31 = lane & 31;
    const int kc0 = (bid + w) & 3;                  // per-wave rotation within a half

    const int lanebase = l5 * 512 + l31 * 16;       // khalf*512 + row*16
    const char* pa = Aws + (size_t)(by * 4 + w) * 65536 + lanebase;
    const char* esrc = Ews + (size_t)bx * 65536;
    const char* el0 = elds + lanebase;

    f16x8 fa[2][2], fb[2][2], ec[2][2], ed[2][2];   // [rowtile/ntile][kstep]
    // A frags for (h=0, kcl=kc0) — issued before LDS staging so they fly early
    {
        const char* pa0 = pa + kc0 * 8192;
        #pragma unroll
        for (int m = 0; m < 2; ++m)
            #pragma unroll
            for (int s = 0; s < 2; ++s) {
                fa[m][s] = ld16(pa0 + m * 2048 + s * 1024);
                fb[m][s] = ld16(pa0 + 4096 + m * 2048 + s * 1024);
            }
    }
    // stage E half-0 (32 KB): 256 threads x 8 x 16B
    #pragma unroll
    for (int j = 0; j < 8; ++j) {
        const int off = j * 4096 + t * 16;
        *(uint4*)(elds + off) = *(const uint4*)(esrc + off);
    }
    __syncthreads();

    f32x16 acc[2][2];                                // [rowtile][ntile]
    #pragma unroll
    for (int m = 0; m < 2; ++m)
        #pragma unroll
        for (int n = 0; n < 2; ++n)
            #pragma unroll
            for (int r = 0; r < 16; ++r) acc[m][n][r] = 0.0f;

    // E frags for first phase
    {
        const char* ep0 = el0 + kc0 * 8192;
        #pragma unroll
        for (int n = 0; n < 2; ++n)
            #pragma unroll
            for (int s = 0; s < 2; ++s) {
                ec[n][s] = ld16(ep0 + n * 2048 + s * 1024);
                ed[n][s] = ld16(ep0 + 4096 + n * 2048 + s * 1024);
            }
    }

#define MFMA32(A, B, C) C = __builtin_amdgcn_mfma_f32_32x32x16_f16(A, B, C, 0, 0, 0)

    #pragma unroll
    for (int h = 0; h < 2; ++h) {
        if (h == 1) {
            __syncthreads();   // all waves done reading half-0
            #pragma unroll
            for (int j = 0; j < 8; ++j) {
                const int off = j * 4096 + t * 16;
                *(uint4*)(elds + off) = *(const uint4*)(esrc + 32768 + off);
            }
            __syncthreads();   // half-1 visible
            const char* ep = el0 + kc0 * 8192;
            #pragma unroll
            for (int n = 0; n < 2; ++n)
                #pragma unroll
                for (int s = 0; s < 2; ++s) {
                    ec[n][s] = ld16(ep + n * 2048 + s * 1024);
                    ed[n][s] = ld16(ep + 4096 + n * 2048 + s * 1024);
                }
        }
        #pragma unroll
        for (int i = 0; i < 4; ++i) {
            const bool last_i = (i == 3);
            const bool reloadA = !(h == 1 && last_i);
            const bool reloadE = !last_i;
            const int kcl_n = (kc0 + i + 1) & 3;
            const int gkcn = last_i ? (4 + kc0) : (h * 4 + kcl_n);
            const char* pan = pa + gkcn * 8192;
            const char* en = el0 + kcl_n * 8192;

            // ---- n = 0: 12 MFMAs, then E[0] early reload ----
            __builtin_amdgcn_s_setprio(1);
            #pragma unroll
            for (int m = 0; m < 2; ++m) {
                MFMA32(fa[m][0], ec[0][0], acc[m][0]);
                MFMA32(fa[m][1], ec[0][1], acc[m][0]);
                MFMA32(fa[m][0], ed[0][0], acc[m][0]);
                MFMA32(fa[m][1], ed[0][1], acc[m][0]);
                MFMA32(fb[m][0], ec[0][0], acc[m][0]);
                MFMA32(fb[m][1], ec[0][1], acc[m][0]);
            }
            __builtin_amdgcn_s_setprio(0);
            if (reloadE) {
                #pragma unroll
                for (int s = 0; s < 2; ++s) {
                    ec[0][s] = ld16(en + s * 1024);
                    ed[0][s] = ld16(en + 4096 + s * 1024);
                }
            }
            // ---- n = 1: 12 MFMAs, then A + E[1] reloads ----
            __builtin_amdgcn_s_setprio(1);
            #pragma unroll
            for (int m = 0; m < 2; ++m) {
                MFMA32(fa[m][0], ec[1][0], acc[m][1]);
                MFMA32(fa[m][1], ec[1][1], acc[m][1]);
                MFMA32(fa[m][0], ed[1][0], acc[m][1]);
                MFMA32(fa[m][1], ed[1][1], acc[m][1]);
                MFMA32(fb[m][0], ec[1][0], acc[m][1]);
                MFMA32(fb[m][1], ec[1][1], acc[m][1]);
            }
            __builtin_amdgcn_s_setprio(0);
            if (reloadA) {
                #pragma unroll
                for (int m = 0; m < 2; ++m)
                    #pragma unroll
                    for (int s = 0; s < 2; ++s) {
                        fa[m][s] = ld16(pan + m * 2048 + s * 1024);
                        fb[m][s] = ld16(pan + 4096 + m * 2048 + s * 1024);
                    }
            }
            if (reloadE) {
                #pragma unroll
                for (int s = 0; s < 2; ++s) {
                    ec[1][s] = ld16(en + 2048 + s * 1024);
                    ed[1][s] = ld16(en + 4096 + 2048 + s * 1024);
                }
            }
        }
    }
#undef MFMA32

    // epilogue: per-wave argmin over its 64 codes; waves own disjoint tokens -> no merge
    // C/D map: col = l31 (+32*n), row(token) = m*32 + (r&3) + 8*(r>>2) + 4*l5
    float eq[2];
    eq[0] = esq[bx * 64 + l31];
    eq[1] = esq[bx * 64 + 32 + l31];
    #pragma unroll
    for (int m = 0; m < 2; ++m) {
        #pragma unroll
        for (int r = 0; r < 16; ++r) {
            const float d0 = fmaf(-2.0f, acc[m][0][r], eq[0]);
            const float d1 = fmaf(-2.0f, acc[m][1][r], eq[1]);
            float bv; int bi;
            if (d1 < d0) { bv = d1; bi = bx * 64 + 32 + l31; }
            else         { bv = d0; bi = bx * 64 + l31; }
            #pragma unroll
            for (int mk = 1; mk < 32; mk <<= 1) {
                const float ov = __shfl_xor(bv, mk);
                const int   oi = __shfl_xor(bi, mk);
                if (ov < bv || (ov == bv && oi < bi)) { bv = ov; bi = oi; }
            }
            if (l31 == 0) {
                const size_t o = (size_t)bx * NTOK + by * 256 + w * 64
                               + m * 32 + (r & 3) + 8 * (r >> 2) + 4 * l5;
                cv[o] = bv; ci[o] = bi;
            }
        }
    }
}

// ---------------- merge 32 candidates + gather quantize ----------------
__global__ __launch_bounds__(256) void merge_gather_kernel(const float* __restrict__ cv,
                                                           const int* __restrict__ ci,
                                                           const float* __restrict__ ew,
                                                           float* __restrict__ out) {
    __shared__ int sIdx[64];
    const int t = threadIdx.x;
    const int n0 = blockIdx.x * 64;
    if (t < 64) {
        const int tok = n0 + t;
        float bv = cv[tok]; int bi = ci[tok];
        #pragma unroll
        for (int s = 1; s < 32; ++s) {
            const float v = cv[(size_t)s * NTOK + tok];
            const int   i2 = ci[(size_t)s * NTOK + tok];
            if (v < bv || (v == bv && i2 < bi)) { bv = v; bi = i2; }
        }
        sIdx[t] = bi;
        out[QOFF + tok] = (float)bi;
    }
    __syncthreads();
    const int b = n0 >> 10, hw0 = n0 & (HW - 1);
    const int i = t & 63, cg = t >> 6;
    const int kidx = sIdx[i];
    const float* er = ew + (size_t)kidx * CDIM;
    float* ob = out + (size_t)b * CDIM * HW + hw0 + i;
    #pragma unroll
    for (int p = 0; p < CDIM / 4; ++p) {
        const int c = cg * 64 + p;
        ob[(size_t)c * HW] = er[c];
    }
}

extern "C" void kernel_launch(void* const* d_in, const int* in_sizes, int n_in,
                              void* d_out, int out_size, void* d_ws, size_t ws_size,
                              hipStream_t stream) {
    const float* x  = (const float*)d_in[0];
    const float* ew = (const float*)d_in[1];
    float* out = (float*)d_out;
    char* ws = (char*)d_ws;

    char*  Aws = ws;                                // 33,554,432 B
    char*  Ews = ws + 33554432;                     //  2,097,152 B
    float* esq = (float*)(ws + 35651584);           //      8,192 B
    float* cvv = (float*)(ws + 35659776);           //  4,194,304 B (32 sets)
    int*   cii = (int*)(ws + 39854080);             //  4,194,304 B

    prep_kernel<<<1280, 256, 0, stream>>>(x, ew, Aws, Ews, esq, out);
    vqmm_kernel<<<4096, 256, 0, stream>>>(Aws, Ews, esq, cvv, cii);
    merge_gather_kernel<<<NTOK / 64, 256, 0, stream>>>(cvv, cii, ew, out);
}

// Round 15
// 135.151 us; speedup vs baseline: 1.5559x; 1.5559x over previous
//
#include <hip/hip_runtime.h>

// VQ codebook assignment via merged single-accumulator split-f16 MFMA GEMM (K=768 effective).
// R15 = R12 (proven 104us) + quarter-granular double-buffered async E staging (T14):
// stage loads issue a full quarter (~1860cy) ahead into regs; barrier waits on nothing.
//   x:       [B=32, C=256, H=32, W=32] f32   -> tokens [32768][256]
//   embed_w: [K=2048, C=256] f32
// out f32: quantize [32,256,32,32] (8388608) | embed_index [32,32,32] (32768 as float) | loss [1]=0
//
// Math (verified R11-R13): xh=f16(64x), xl=f16(64x-xh); eh=f16(2^15 e), el=f16(2^15 e - eh).
//   acc = sum xh*eh + xh*el + xl*eh == 2^21*dot - sum(xl*el)  (dropped ~1e-6 rel)
//   d = 2^21*esq - 2*acc ; argmin preserved.
//
// Register law (R4/R8/R10): pool 512/SIMD; 3 waves/SIMD => <=170/wave.
//   acc 64 (AGPR) + A 32 + E 32 + stage 16 + misc ~20 = ~164. Tripwire: WRITE_SIZE/VGPR.
// R3: no global_load_lds. R14: 32x32 shape falsified -> 16x16x32 kept.
//
// ws fragment-panel layout (R12):
//   A: [panel 512][kc 8][limb 2][slot 4][row 64][16B]  = 32 MB   (64 tokens/panel)
//   E: [panel 32 ][kc 8][limb 2][slot 4][code 64][16B] =  2 MB   (64 codes/panel)

#define CDIM 256
#define KDIM 2048
#define HW   1024
#define NTOK 32768
#define QOFF 8388608
#define LOFF (QOFF + NTOK)

typedef _Float16 f16x8 __attribute__((ext_vector_type(8)));
typedef float    f32x4 __attribute__((ext_vector_type(4)));

__device__ __forceinline__ f16x8 ld16(const char* p) { return *(const f16x8*)(p); }

// ---------------- fused prep: blocks 0..1023 = X transpose, 1024..1279 = E limbs ----------------
__global__ __launch_bounds__(256) void prep_kernel(const float* __restrict__ x,
                                                   const float* __restrict__ ew,
                                                   char* __restrict__ Aws,
                                                   char* __restrict__ Ews,
                                                   float* __restrict__ esq,
                                                   float* __restrict__ out) {
    __shared__ float tile[32][257];
    const int t = threadIdx.x;
    if (blockIdx.x < 1024) {
        const int bid = blockIdx.x;              // 32 b * 8 kc * 4 hwblk
        const int b = bid >> 5;
        const int kc = (bid >> 2) & 7;
        const int c0 = kc * 32;
        const int hw0 = (bid & 3) * 256;
        #pragma unroll 8
        for (int r = 0; r < 32; ++r)
            tile[r][t] = x[((size_t)(b * CDIM + c0 + r) << 10) + hw0 + t];
        __syncthreads();
        union { _Float16 h[32]; uint4 q[4]; } Hb, Lb;
        #pragma unroll 8
        for (int r = 0; r < 32; ++r) {
            const float xs = tile[r][t] * 64.0f;
            const _Float16 hh = (_Float16)xs;
            Hb.h[r] = hh;
            Lb.h[r] = (_Float16)(xs - (float)hh);
        }
        const int tok = b * HW + hw0 + t;
        const int p = tok >> 6, row = tok & 63;
        char* d = Aws + (size_t)p * 65536 + kc * 8192 + row * 16;
        #pragma unroll
        for (int g = 0; g < 4; ++g) {
            *(uint4*)(d + g * 1024)        = Hb.q[g];   // high limb
            *(uint4*)(d + 4096 + g * 1024) = Lb.q[g];   // low limb
        }
    } else {
        const int bid = blockIdx.x - 1024;             // 256 blocks x 8 codes
        const int code = bid * 8 + (t >> 5);
        const int u = t & 31;
        const float4 v0 = *(const float4*)&ew[(size_t)code * CDIM + u * 8];
        const float4 v1 = *(const float4*)&ew[(size_t)code * CDIM + u * 8 + 4];
        float s = v0.x*v0.x + v0.y*v0.y + v0.z*v0.z + v0.w*v0.w
                + v1.x*v1.x + v1.y*v1.y + v1.z*v1.z + v1.w*v1.w;
        #pragma unroll
        for (int m = 16; m >= 1; m >>= 1) s += __shfl_xor(s, m, 32);
        if (u == 0) esq[code] = s * 2097152.0f;        // 2^21 * esq
        const float e[8] = {v0.x, v0.y, v0.z, v0.w, v1.x, v1.y, v1.z, v1.w};
        union { _Float16 h[8]; uint4 q; } H, L;
        #pragma unroll
        for (int j = 0; j < 8; ++j) {
            const float ev = e[j] * 32768.0f;          // 2^15 * e
            const _Float16 hh = (_Float16)ev;
            H.h[j] = hh;
            L.h[j] = (_Float16)(ev - (float)hh);
        }
        const int kc = u >> 2, g = u & 3;
        const int p = code >> 6, row = code & 63;
        char* d = Ews + (size_t)p * 65536 + kc * 8192 + g * 1024 + row * 16;
        *(uint4*)d = H.q;
        *(uint4*)(d + 4096) = L.q;
        if (bid == 0 && t == 0) out[LOFF] = 0.0f;
    }
}

// ---------------- fused MFMA GEMM + argmin: quarter-dbuf async-staged LDS-E ----------------
// Block = 4 waves x 64 tokens (256 tokens) over ONE shared 64-code panel.
// Quarter = 2 kc chunks (16KB). elds = 2 quarter buffers. One barrier per quarter,
// with the staged data already in regs (global loads issued a full quarter earlier).
__global__ __launch_bounds__(256, 3) void vqmm_kernel(const char* __restrict__ Aws,
                                                      const char* __restrict__ Ews,
                                                      const float* __restrict__ esq,
                                                      float* __restrict__ cv,
                                                      int* __restrict__ ci) {
    __shared__ __align__(16) char elds[32768];   // buf0 | buf1 (16KB each = 2 kc chunks)

    const int t = threadIdx.x;
    const int bid = blockIdx.x;                     // 4096 blocks
    // bijective XCD-grouped swizzle: the 32 code-panels of one token-group share bid%8
    const int by = (bid & 7) | ((bid >> 8) << 3);   // token group 0..127 (256 tokens)
    const int bx = (bid >> 3) & 31;                 // code panel 0..31   (64 codes)
    const int lane = t & 63, w = t >> 6;
    const int g = lane >> 4, lr = lane & 15;
    const int r = (bid + w) & 1;                    // intra-quarter rotation (anti-lockstep)

    const char* pa = Aws + (size_t)(by * 4 + w) * 65536 + g * 1024 + lr * 16;
    const char* esrc = Ews + (size_t)bx * 65536;

    f16x8 fa[4], fb[4], ec[4], ed[4];
    uint4 rg[4];

    // prologue: stage quarter 0 -> buf0; A frags for first phase (kc = r)
    #pragma unroll
    for (int j = 0; j < 4; ++j)
        rg[j] = *(const uint4*)(esrc + j * 4096 + t * 16);
    {
        const char* pa0 = pa + r * 8192;
        #pragma unroll
        for (int m = 0; m < 4; ++m) {
            fa[m] = ld16(pa0 + m * 256);
            fb[m] = ld16(pa0 + 4096 + m * 256);
        }
    }
    #pragma unroll
    for (int j = 0; j < 4; ++j)
        *(uint4*)(elds + j * 4096 + t * 16) = rg[j];
    __syncthreads();

    const f32x4 zf = {0.f, 0.f, 0.f, 0.f};
    f32x4 acc[4][4];
    #pragma unroll
    for (int m = 0; m < 4; ++m)
        #pragma unroll
        for (int n = 0; n < 4; ++n) acc[m][n] = zf;

    // E frags for first phase (buf0, local kc = r)
    {
        const char* ep0 = elds + r * 8192 + g * 1024 + lr * 16;
        #pragma unroll
        for (int n = 0; n < 4; ++n) {
            ec[n] = ld16(ep0 + n * 256);
            ed[n] = ld16(ep0 + 4096 + n * 256);
        }
    }

    #pragma unroll
    for (int q = 0; q < 4; ++q) {
        const int buf = (q & 1) * 16384;
        // issue stage loads for quarter q+1 (fly under 2 phases of MFMA, ~1860 cyc)
        if (q < 3) {
            const char* s2 = esrc + (q + 1) * 16384;
            #pragma unroll
            for (int j = 0; j < 4; ++j)
                rg[j] = *(const uint4*)(s2 + j * 4096 + t * 16);
        }
        // head E-frag load for this quarter (q>0; q==0 loaded in prologue)
        if (q > 0) {
            const char* ep = elds + buf + r * 8192 + g * 1024 + lr * 16;
            #pragma unroll
            for (int n = 0; n < 4; ++n) {
                ec[n] = ld16(ep + n * 256);
                ed[n] = ld16(ep + 4096 + n * 256);
            }
        }
        #pragma unroll
        for (int p = 0; p < 2; ++p) {
            const bool lastPhase = (q == 3) && (p == 1);
            // A chunk for the NEXT phase: within quarter -> 2q + (r^1); across -> 2(q+1) + r
            const int kcA = (p == 0) ? (2 * q + (r ^ 1)) : (2 * (q + 1) + r);
            const char* pan = pa + kcA * 8192;
            #pragma unroll
            for (int m = 0; m < 4; ++m) {
                __builtin_amdgcn_s_setprio(1);
                #pragma unroll
                for (int n = 0; n < 4; ++n) {
                    acc[m][n] = __builtin_amdgcn_mfma_f32_16x16x32_f16(fa[m], ec[n], acc[m][n], 0, 0, 0);
                    acc[m][n] = __builtin_amdgcn_mfma_f32_16x16x32_f16(fa[m], ed[n], acc[m][n], 0, 0, 0);
                    acc[m][n] = __builtin_amdgcn_mfma_f32_16x16x32_f16(fb[m], ec[n], acc[m][n], 0, 0, 0);
                }
                __builtin_amdgcn_s_setprio(0);
                // A reload-in-place right after fa[m]/fb[m]'s last use (covered by m+1.. MFMAs)
                if (!lastPhase) {
                    fa[m] = ld16(pan + m * 256);
                    fb[m] = ld16(pan + 4096 + m * 256);
                }
            }
            // E reload for phase p=1 (same buf, local kc = r^1); quarter-head load covers p=0
            if (p == 0) {
                const char* en = elds + buf + (r ^ 1) * 8192 + g * 1024 + lr * 16;
                #pragma unroll
                for (int n = 0; n < 4; ++n) {
                    ec[n] = ld16(en + n * 256);
                    ed[n] = ld16(en + 4096 + n * 256);
                }
            }
        }
        // write staged quarter q+1 into the other buffer (its readers finished in q-1)
        if (q < 3) {
            char* nb = elds + ((q + 1) & 1) * 16384;
            #pragma unroll
            for (int j = 0; j < 4; ++j)
                *(uint4*)(nb + j * 4096 + t * 16) = rg[j];
            __syncthreads();
        }
    }

    // epilogue: per-wave argmin over its 64 codes; waves own disjoint tokens -> no merge
    float eq[4];
    #pragma unroll
    for (int n = 0; n < 4; ++n) eq[n] = esq[bx * 64 + n * 16 + lr];
    #pragma unroll
    for (int m = 0; m < 4; ++m) {
        #pragma unroll
        for (int rr = 0; rr < 4; ++rr) {
            float bv = 3.4e38f; int bi = 0x7fffffff;
            #pragma unroll
            for (int n = 0; n < 4; ++n) {
                const float d = fmaf(-2.0f, acc[m][n][rr], eq[n]);
                const int cidx = bx * 64 + n * 16 + lr;
                if (d < bv) { bv = d; bi = cidx; }
            }
            #pragma unroll
            for (int mk = 1; mk < 16; mk <<= 1) {
                const float ov = __shfl_xor(bv, mk, 16);
                const int   oi = __shfl_xor(bi, mk, 16);
                if (ov < bv || (ov == bv && oi < bi)) { bv = ov; bi = oi; }
            }
            if (lr == 0) {
                const size_t o = (size_t)bx * NTOK + by * 256 + w * 64 + m * 16 + g * 4 + rr;
                cv[o] = bv; ci[o] = bi;
            }
        }
    }
}

// ---------------- merge 32 candidates + gather quantize (s-slices parallelized) ----------------
__global__ __launch_bounds__(256) void merge_gather_kernel(const float* __restrict__ cv,
                                                           const int* __restrict__ ci,
                                                           const float* __restrict__ ew,
                                                           float* __restrict__ out) {
    __shared__ float redV[256];
    __shared__ int   redI[256];
    __shared__ int   sIdx[64];
    const int t = threadIdx.x;
    const int n0 = blockIdx.x * 64;
    {
        const int tok = n0 + (t & 63);
        const int s0 = (t >> 6) * 8;               // 4 slices of 8 candidate sets
        float bv = 3.4e38f; int bi = 0x7fffffff;
        #pragma unroll
        for (int s = 0; s < 8; ++s) {
            const float v  = cv[(size_t)(s0 + s) * NTOK + tok];
            const int   i2 = ci[(size_t)(s0 + s) * NTOK + tok];
            if (v < bv || (v == bv && i2 < bi)) { bv = v; bi = i2; }
        }
        redV[t] = bv; redI[t] = bi;
    }
    __syncthreads();
    if (t < 64) {
        float bv = redV[t]; int bi = redI[t];
        #pragma unroll
        for (int s = 1; s < 4; ++s) {
            const float v = redV[t + s * 64]; const int i2 = redI[t + s * 64];
            if (v < bv || (v == bv && i2 < bi)) { bv = v; bi = i2; }
        }
        sIdx[t] = bi;
        out[QOFF + n0 + t] = (float)bi;
    }
    __syncthreads();
    const int b = n0 >> 10, hw0 = n0 & (HW - 1);
    const int i = t & 63, cg = t >> 6;
    const int kidx = sIdx[i];
    const float* er = ew + (size_t)kidx * CDIM;
    float* ob = out + (size_t)b * CDIM * HW + hw0 + i;
    #pragma unroll
    for (int p = 0; p < CDIM / 4; ++p) {
        const int c = cg * 64 + p;
        ob[(size_t)c * HW] = er[c];
    }
}

extern "C" void kernel_launch(void* const* d_in, const int* in_sizes, int n_in,
                              void* d_out, int out_size, void* d_ws, size_t ws_size,
                              hipStream_t stream) {
    const float* x  = (const float*)d_in[0];
    const float* ew = (const float*)d_in[1];
    float* out = (float*)d_out;
    char* ws = (char*)d_ws;

    char*  Aws = ws;                                // 33,554,432 B
    char*  Ews = ws + 33554432;                     //  2,097,152 B
    float* esq = (float*)(ws + 35651584);           //      8,192 B
    float* cvv = (float*)(ws + 35659776);           //  4,194,304 B (32 sets)
    int*   cii = (int*)(ws + 39854080);             //  4,194,304 B

    prep_kernel<<<1280, 256, 0, stream>>>(x, ew, Aws, Ews, esq, out);
    vqmm_kernel<<<4096, 256, 0, stream>>>(Aws, Ews, esq, cvv, cii);
    merge_gather_kernel<<<NTOK / 64, 256, 0, stream>>>(cvv, cii, ew, out);
}